// Round 1
// baseline (2842.607 us; speedup 1.0000x reference)
//
#include <hip/hip_runtime.h>

#define NN 100000
#define NE 3200000

// ---- transpose the 64x64 weight matrices (3 lin layers + final fc) ----
__global__ __launch_bounds__(256) void k_transpose(
    const float* __restrict__ linw, const float* __restrict__ fcw,
    float* __restrict__ wt)
{
    const float* src = (blockIdx.x < 3) ? (linw + blockIdx.x * 4096) : fcw;
    float* dst = wt + blockIdx.x * 4096;
    for (int i = threadIdx.x; i < 4096; i += 256)
        dst[(i & 63) * 64 + (i >> 6)] = src[i];   // wt[k][j] = w[j][k]
}

// ---- per-edge softplus weights for all 3 layers in one pass over edge_attr ----
__global__ __launch_bounds__(256) void k_edge_w(
    const float* __restrict__ ea, const float* __restrict__ mw,
    const float* __restrict__ mb, float* __restrict__ wout)
{
    float wl[3][8], bl[3];
    #pragma unroll
    for (int l = 0; l < 3; ++l) {
        bl[l] = mb[l];
        #pragma unroll
        for (int k = 0; k < 8; ++k) wl[l][k] = mw[l * 8 + k];
    }
    int stride = gridDim.x * blockDim.x;
    const float4* ea4 = (const float4*)ea;
    for (int e = blockIdx.x * blockDim.x + threadIdx.x; e < NE; e += stride) {
        float4 a0 = ea4[2 * e], a1 = ea4[2 * e + 1];
        float av[8] = {a0.x, a0.y, a0.z, a0.w, a1.x, a1.y, a1.z, a1.w};
        #pragma unroll
        for (int l = 0; l < 3; ++l) {
            float xx = bl[l];
            #pragma unroll
            for (int k = 0; k < 8; ++k) xx += av[k] * wl[l][k];
            // numerically stable softplus = max(x,0) + log1p(exp(-|x|))
            wout[l * NE + e] = fmaxf(xx, 0.f) + log1pf(expf(-fabsf(xx)));
        }
    }
}

// ---- scatter: agg[dst] += w*h[src]; wsum[dst] += w  (the -w*h[dst] term is
//      folded into k_node as -wsum[n]*h[n], halving the gather traffic) ----
__global__ __launch_bounds__(256) void k_scatter(
    const int* __restrict__ ei, const float* __restrict__ w,
    const float* __restrict__ h, float* __restrict__ agg,
    float* __restrict__ wsum)
{
    int lane = threadIdx.x & 63;
    int gw = (blockIdx.x * blockDim.x + threadIdx.x) >> 6;
    int nw = (gridDim.x * blockDim.x) >> 6;
    for (int e = gw; e < NE; e += nw) {
        int src = ei[e];        // edge_index[0] = x_j (source)
        int dst = ei[NE + e];   // edge_index[1] = x_i (aggregation target)
        float we = w[e];
        float hs = h[src * 64 + lane];
        atomicAdd(&agg[dst * 64 + lane], we * hs);
        if (lane == 0) atomicAdd(&wsum[dst], we);
    }
}

// ---- fused: a = agg - wsum*h ; y = relu(a @ W^T + b) ; LN ; +residual ----
// One thread per node. wt is transposed so wt[k*64+j] access is wave-uniform
// -> compiler emits s_load + v_fmac (SGPR operand): no LDS, no shuffles.
__global__ __launch_bounds__(256) void k_node(
    const float* __restrict__ agg, const float* __restrict__ wsum,
    const float* __restrict__ hin, float* __restrict__ hout,
    const float* __restrict__ wt, const float* __restrict__ bias,
    const float* __restrict__ gamma, const float* __restrict__ beta)
{
    int n0 = blockIdx.x * blockDim.x + threadIdx.x;
    int stride = gridDim.x * blockDim.x;
    const float4* agg4 = (const float4*)agg;
    const float4* hin4 = (const float4*)hin;
    float4* ho4 = (float4*)hout;
    for (int n = n0; n < NN; n += stride) {
        float wsn = wsum[n];
        float y[64];
        #pragma unroll
        for (int j = 0; j < 64; ++j) y[j] = bias[j];
        #pragma unroll 2
        for (int k4 = 0; k4 < 16; ++k4) {
            float4 g = agg4[n * 16 + k4];
            float4 hh = hin4[n * 16 + k4];
            float av[4] = {g.x - wsn * hh.x, g.y - wsn * hh.y,
                           g.z - wsn * hh.z, g.w - wsn * hh.w};
            #pragma unroll
            for (int kk = 0; kk < 4; ++kk) {
                const float* wr = wt + (k4 * 4 + kk) * 64;
                #pragma unroll
                for (int j = 0; j < 64; ++j) y[j] += av[kk] * wr[j];
            }
        }
        float s = 0.f, s2 = 0.f;
        #pragma unroll
        for (int j = 0; j < 64; ++j) {
            y[j] = fmaxf(y[j], 0.f);
            s += y[j]; s2 += y[j] * y[j];
        }
        float mu = s * (1.f / 64.f);
        float var = s2 * (1.f / 64.f) - mu * mu;
        float inv = rsqrtf(var + 1e-5f);
        #pragma unroll
        for (int j4 = 0; j4 < 16; ++j4) {
            float4 hh = hin4[n * 16 + j4];
            float4 o;
            o.x = (y[4*j4+0] - mu) * inv * gamma[4*j4+0] + beta[4*j4+0] + hh.x;
            o.y = (y[4*j4+1] - mu) * inv * gamma[4*j4+1] + beta[4*j4+1] + hh.y;
            o.z = (y[4*j4+2] - mu) * inv * gamma[4*j4+2] + beta[4*j4+2] + hh.z;
            o.w = (y[4*j4+3] - mu) * inv * gamma[4*j4+3] + beta[4*j4+3] + hh.w;
            ho4[n * 16 + j4] = o;
        }
    }
}

// ---- final fc: out = h @ fc_w^T + fc_b ----
__global__ __launch_bounds__(256) void k_fc(
    const float* __restrict__ hin, float* __restrict__ out,
    const float* __restrict__ wt, const float* __restrict__ bias)
{
    int n0 = blockIdx.x * blockDim.x + threadIdx.x;
    int stride = gridDim.x * blockDim.x;
    const float4* hin4 = (const float4*)hin;
    float4* o4 = (float4*)out;
    for (int n = n0; n < NN; n += stride) {
        float y[64];
        #pragma unroll
        for (int j = 0; j < 64; ++j) y[j] = bias[j];
        #pragma unroll 2
        for (int k4 = 0; k4 < 16; ++k4) {
            float4 hh = hin4[n * 16 + k4];
            float hv[4] = {hh.x, hh.y, hh.z, hh.w};
            #pragma unroll
            for (int kk = 0; kk < 4; ++kk) {
                const float* wr = wt + (k4 * 4 + kk) * 64;
                #pragma unroll
                for (int j = 0; j < 64; ++j) y[j] += hv[kk] * wr[j];
            }
        }
        #pragma unroll
        for (int j4 = 0; j4 < 16; ++j4) {
            float4 o = {y[4*j4], y[4*j4+1], y[4*j4+2], y[4*j4+3]};
            o4[n * 16 + j4] = o;
        }
    }
}

extern "C" void kernel_launch(void* const* d_in, const int* in_sizes, int n_in,
                              void* d_out, int out_size, void* d_ws, size_t ws_size,
                              hipStream_t stream)
{
    const float* x     = (const float*)d_in[0];
    const int*   ei    = (const int*)d_in[1];
    const float* ea    = (const float*)d_in[2];
    const float* linw  = (const float*)d_in[3];
    const float* linb  = (const float*)d_in[4];
    const float* mw    = (const float*)d_in[5];
    const float* mb    = (const float*)d_in[6];
    const float* gamma = (const float*)d_in[7];
    const float* beta  = (const float*)d_in[8];
    const float* fcw   = (const float*)d_in[9];
    const float* fcb   = (const float*)d_in[10];
    float* out = (float*)d_out;

    float* ws   = (float*)d_ws;
    float* hA   = ws;                          // N*64
    float* hB   = hA + (size_t)NN * 64;        // N*64
    float* agg  = hB + (size_t)NN * 64;        // N*64
    float* wsum = agg + (size_t)NN * 64;       // N   (contiguous with agg for one memset)
    float* wedg = wsum + NN;                   // 3*E
    float* wt   = wedg + (size_t)3 * NE;       // 4*4096

    k_transpose<<<4, 256, 0, stream>>>(linw, fcw, wt);
    k_edge_w<<<2048, 256, 0, stream>>>(ea, mw, mb, wedg);

    const float* cur = x;
    for (int l = 0; l < 3; ++l) {
        hipMemsetAsync(agg, 0, ((size_t)NN * 64 + NN) * sizeof(float), stream);
        k_scatter<<<2048, 256, 0, stream>>>(ei, wedg + (size_t)l * NE, cur, agg, wsum);
        float* nxt = (l == 1) ? hB : hA;       // l=0: x->hA, l=1: hA->hB, l=2: hB->hA
        k_node<<<512, 256, 0, stream>>>(agg, wsum, cur, nxt,
                                        wt + l * 4096, linb + l * 64,
                                        gamma + l * 64, beta + l * 64);
        cur = nxt;
    }
    k_fc<<<512, 256, 0, stream>>>(cur, out, wt + 3 * 4096, fcb);
}

// Round 2
// 1104.963 us; speedup vs baseline: 2.5726x; 2.5726x over previous
//
#include <hip/hip_runtime.h>

#define NN 100000
#define NE 3200000
#define NCHUNK 98   // ceil(NN / 1024)

// ---- transpose the 64x64 weight matrices (3 lin layers + final fc) ----
__global__ __launch_bounds__(256) void k_transpose(
    const float* __restrict__ linw, const float* __restrict__ fcw,
    float* __restrict__ wt)
{
    const float* src = (blockIdx.x < 3) ? (linw + blockIdx.x * 4096) : fcw;
    float* dst = wt + blockIdx.x * 4096;
    for (int i = threadIdx.x; i < 4096; i += 256)
        dst[(i & 63) * 64 + (i >> 6)] = src[i];   // wt[k][j] = w[j][k]
}

// ---- histogram of dst degrees ----
__global__ __launch_bounds__(256) void k_hist(
    const int* __restrict__ ei, int* __restrict__ deg)
{
    int stride = gridDim.x * blockDim.x;
    for (int e = blockIdx.x * blockDim.x + threadIdx.x; e < NE; e += stride)
        atomicAdd(&deg[ei[NE + e]], 1);
}

// ---- hierarchical exclusive scan: 1024-elem chunks ----
__global__ __launch_bounds__(256) void k_scan1(
    const int* __restrict__ deg, int* __restrict__ base, int* __restrict__ csum)
{
    __shared__ int lds[256];
    int tid = threadIdx.x;
    int i0 = blockIdx.x * 1024 + tid * 4;
    int d[4];
    #pragma unroll
    for (int k = 0; k < 4; ++k) d[k] = (i0 + k < NN) ? deg[i0 + k] : 0;
    int s = d[0] + d[1] + d[2] + d[3];
    lds[tid] = s;
    __syncthreads();
    for (int off = 1; off < 256; off <<= 1) {
        int add = (tid >= off) ? lds[tid - off] : 0;
        __syncthreads();
        lds[tid] += add;
        __syncthreads();
    }
    int excl = lds[tid] - s;
    if (i0 + 0 < NN) base[i0 + 0] = excl;
    if (i0 + 1 < NN) base[i0 + 1] = excl + d[0];
    if (i0 + 2 < NN) base[i0 + 2] = excl + d[0] + d[1];
    if (i0 + 3 < NN) base[i0 + 3] = excl + d[0] + d[1] + d[2];
    if (tid == 255) csum[blockIdx.x] = lds[255];
}

__global__ __launch_bounds__(128) void k_scan2(
    const int* __restrict__ csum, int* __restrict__ coff)
{
    __shared__ int lds[128];
    int tid = threadIdx.x;
    int v = (tid < NCHUNK) ? csum[tid] : 0;
    lds[tid] = v;
    __syncthreads();
    for (int off = 1; off < 128; off <<= 1) {
        int add = (tid >= off) ? lds[tid - off] : 0;
        __syncthreads();
        lds[tid] += add;
        __syncthreads();
    }
    coff[tid] = lds[tid] - v;   // exclusive
}

__global__ __launch_bounds__(256) void k_scan3(
    int* __restrict__ base, int* __restrict__ cursor, const int* __restrict__ coff)
{
    int off = coff[blockIdx.x];
    int i0 = blockIdx.x * 1024 + threadIdx.x * 4;
    #pragma unroll
    for (int k = 0; k < 4; ++k)
        if (i0 + k < NN) {
            int b = base[i0 + k] + off;
            base[i0 + k] = b;
            cursor[i0 + k] = b;
        }
    if (blockIdx.x == 0 && threadIdx.x == 0) base[NN] = NE;
}

// ---- fill CSR slots: pk[slot] = {src, w0, w1, w2} (softplus fused here) ----
__global__ __launch_bounds__(256) void k_fill(
    const int* __restrict__ ei, const float* __restrict__ ea,
    const float* __restrict__ mw, const float* __restrict__ mb,
    int* __restrict__ cursor, float4* __restrict__ pk)
{
    float wl[3][8], bl[3];
    #pragma unroll
    for (int l = 0; l < 3; ++l) {
        bl[l] = mb[l];
        #pragma unroll
        for (int k = 0; k < 8; ++k) wl[l][k] = mw[l * 8 + k];
    }
    int stride = gridDim.x * blockDim.x;
    const float4* ea4 = (const float4*)ea;
    for (int e = blockIdx.x * blockDim.x + threadIdx.x; e < NE; e += stride) {
        float4 a0 = ea4[2 * e], a1 = ea4[2 * e + 1];
        float av[8] = {a0.x, a0.y, a0.z, a0.w, a1.x, a1.y, a1.z, a1.w};
        float w[3];
        #pragma unroll
        for (int l = 0; l < 3; ++l) {
            float xx = bl[l];
            #pragma unroll
            for (int k = 0; k < 8; ++k) xx += av[k] * wl[l][k];
            w[l] = fmaxf(xx, 0.f) + log1pf(expf(-fabsf(xx)));  // stable softplus
        }
        int src = ei[e], dst = ei[NE + e];
        int slot = atomicAdd(&cursor[dst], 1);
        pk[slot] = make_float4(__int_as_float(src), w[0], w[1], w[2]);
    }
}

// ---- atomic-free aggregation: wave per node, lane = channel ----
// aout[n] = sum_e w_e * h[src_e] - (sum_e w_e) * h[n]
template<int L>
__global__ __launch_bounds__(256) void k_agg(
    const int* __restrict__ base, const float4* __restrict__ pk,
    const float* __restrict__ h, float* __restrict__ aout)
{
    int lane = threadIdx.x & 63;
    int gw = (blockIdx.x * blockDim.x + threadIdx.x) >> 6;
    int nw = (gridDim.x * blockDim.x) >> 6;
    for (int n = gw; n < NN; n += nw) {
        int s = base[n], e2 = base[n + 1];
        float acc = 0.f, wsn = 0.f;
        int sl = s;
        for (; sl + 4 <= e2; sl += 4) {
            float4 p0 = pk[sl], p1 = pk[sl + 1], p2 = pk[sl + 2], p3 = pk[sl + 3];
            float w0 = (L == 0) ? p0.y : (L == 1) ? p0.z : p0.w;
            float w1 = (L == 0) ? p1.y : (L == 1) ? p1.z : p1.w;
            float w2 = (L == 0) ? p2.y : (L == 1) ? p2.z : p2.w;
            float w3 = (L == 0) ? p3.y : (L == 1) ? p3.z : p3.w;
            float h0 = h[__float_as_int(p0.x) * 64 + lane];
            float h1 = h[__float_as_int(p1.x) * 64 + lane];
            float h2 = h[__float_as_int(p2.x) * 64 + lane];
            float h3 = h[__float_as_int(p3.x) * 64 + lane];
            acc += w0 * h0; acc += w1 * h1; acc += w2 * h2; acc += w3 * h3;
            wsn += w0 + w1 + w2 + w3;
        }
        for (; sl < e2; ++sl) {
            float4 p = pk[sl];
            float w = (L == 0) ? p.y : (L == 1) ? p.z : p.w;
            acc += w * h[__float_as_int(p.x) * 64 + lane];
            wsn += w;
        }
        aout[n * 64 + lane] = acc - wsn * h[n * 64 + lane];
    }
}

// ---- fused: y = relu(a @ W^T + b) ; LN ; +residual ----
// NOTE: hout may alias a (per-row in-place) -> no __restrict on those two.
__global__ __launch_bounds__(256) void k_node(
    const float* a, const float* __restrict__ hin, float* hout,
    const float* __restrict__ wt, const float* __restrict__ bias,
    const float* __restrict__ gamma, const float* __restrict__ beta)
{
    int n0 = blockIdx.x * blockDim.x + threadIdx.x;
    int stride = gridDim.x * blockDim.x;
    const float4* a4 = (const float4*)a;
    const float4* hin4 = (const float4*)hin;
    float4* ho4 = (float4*)hout;
    for (int n = n0; n < NN; n += stride) {
        float y[64];
        #pragma unroll
        for (int j = 0; j < 64; ++j) y[j] = bias[j];
        #pragma unroll 2
        for (int k4 = 0; k4 < 16; ++k4) {
            float4 g = a4[n * 16 + k4];
            float av[4] = {g.x, g.y, g.z, g.w};
            #pragma unroll
            for (int kk = 0; kk < 4; ++kk) {
                const float* wr = wt + (k4 * 4 + kk) * 64;
                #pragma unroll
                for (int j = 0; j < 64; ++j) y[j] += av[kk] * wr[j];
            }
        }
        float s = 0.f, s2 = 0.f;
        #pragma unroll
        for (int j = 0; j < 64; ++j) {
            y[j] = fmaxf(y[j], 0.f);
            s += y[j]; s2 += y[j] * y[j];
        }
        float mu = s * (1.f / 64.f);
        float var = s2 * (1.f / 64.f) - mu * mu;
        float inv = rsqrtf(var + 1e-5f);
        #pragma unroll
        for (int j4 = 0; j4 < 16; ++j4) {
            float4 hh = hin4[n * 16 + j4];
            float4 o;
            o.x = (y[4*j4+0] - mu) * inv * gamma[4*j4+0] + beta[4*j4+0] + hh.x;
            o.y = (y[4*j4+1] - mu) * inv * gamma[4*j4+1] + beta[4*j4+1] + hh.y;
            o.z = (y[4*j4+2] - mu) * inv * gamma[4*j4+2] + beta[4*j4+2] + hh.z;
            o.w = (y[4*j4+3] - mu) * inv * gamma[4*j4+3] + beta[4*j4+3] + hh.w;
            ho4[n * 16 + j4] = o;
        }
    }
}

// ---- final fc: out = h @ fc_w^T + fc_b ----
__global__ __launch_bounds__(256) void k_fc(
    const float* __restrict__ hin, float* __restrict__ out,
    const float* __restrict__ wt, const float* __restrict__ bias)
{
    int n0 = blockIdx.x * blockDim.x + threadIdx.x;
    int stride = gridDim.x * blockDim.x;
    const float4* hin4 = (const float4*)hin;
    float4* o4 = (float4*)out;
    for (int n = n0; n < NN; n += stride) {
        float y[64];
        #pragma unroll
        for (int j = 0; j < 64; ++j) y[j] = bias[j];
        #pragma unroll 2
        for (int k4 = 0; k4 < 16; ++k4) {
            float4 hh = hin4[n * 16 + k4];
            float hv[4] = {hh.x, hh.y, hh.z, hh.w};
            #pragma unroll
            for (int kk = 0; kk < 4; ++kk) {
                const float* wr = wt + (k4 * 4 + kk) * 64;
                #pragma unroll
                for (int j = 0; j < 64; ++j) y[j] += hv[kk] * wr[j];
            }
        }
        #pragma unroll
        for (int j4 = 0; j4 < 16; ++j4) {
            float4 o = {y[4*j4], y[4*j4+1], y[4*j4+2], y[4*j4+3]};
            o4[n * 16 + j4] = o;
        }
    }
}

extern "C" void kernel_launch(void* const* d_in, const int* in_sizes, int n_in,
                              void* d_out, int out_size, void* d_ws, size_t ws_size,
                              hipStream_t stream)
{
    const float* x     = (const float*)d_in[0];
    const int*   ei    = (const int*)d_in[1];
    const float* ea    = (const float*)d_in[2];
    const float* linw  = (const float*)d_in[3];
    const float* linb  = (const float*)d_in[4];
    const float* mw    = (const float*)d_in[5];
    const float* mb    = (const float*)d_in[6];
    const float* gamma = (const float*)d_in[7];
    const float* beta  = (const float*)d_in[8];
    const float* fcw   = (const float*)d_in[9];
    const float* fcb   = (const float*)d_in[10];
    float* out = (float*)d_out;

    // workspace layout (~104 MB)
    float*  A    = (float*)d_ws;                   // NN*64
    float*  C    = A + (size_t)NN * 64;            // NN*64
    float4* pk   = (float4*)(C + (size_t)NN * 64); // NE float4
    float*  wt   = (float*)(pk + (size_t)NE);      // 4*4096
    int*    deg  = (int*)(wt + 4 * 4096);          // NN
    int*    base = deg + NN;                       // NN+1
    int*    cur  = base + NN + 1;                  // NN
    int*    csum = cur + NN;                       // 128
    int*    coff = csum + 128;                     // 128

    k_transpose<<<4, 256, 0, stream>>>(linw, fcw, wt);
    hipMemsetAsync(deg, 0, NN * sizeof(int), stream);
    k_hist<<<2048, 256, 0, stream>>>(ei, deg);
    k_scan1<<<NCHUNK, 256, 0, stream>>>(deg, base, csum);
    k_scan2<<<1, 128, 0, stream>>>(csum, coff);
    k_scan3<<<NCHUNK, 256, 0, stream>>>(base, cur, coff);
    k_fill<<<2048, 256, 0, stream>>>(ei, ea, mw, mb, cur, pk);

    // l0: x -> C ; l1: C -> A ; l2: A -> C
    k_agg<0><<<2560, 256, 0, stream>>>(base, pk, x, C);
    k_node<<<512, 256, 0, stream>>>(C, x, C, wt + 0 * 4096, linb + 0 * 64,
                                    gamma + 0 * 64, beta + 0 * 64);
    k_agg<1><<<2560, 256, 0, stream>>>(base, pk, C, A);
    k_node<<<512, 256, 0, stream>>>(A, C, A, wt + 1 * 4096, linb + 1 * 64,
                                    gamma + 1 * 64, beta + 1 * 64);
    k_agg<2><<<2560, 256, 0, stream>>>(base, pk, A, C);
    k_node<<<512, 256, 0, stream>>>(C, A, C, wt + 2 * 4096, linb + 2 * 64,
                                    gamma + 2 * 64, beta + 2 * 64);

    k_fc<<<512, 256, 0, stream>>>(C, out, wt + 3 * 4096, fcb);
}

// Round 4
// 1004.024 us; speedup vs baseline: 2.8312x; 1.1005x over previous
//
#include <hip/hip_runtime.h>

#define NN 100000
#define NE 3200000
#define NCHUNK 98   // ceil(NN / 1024)

__device__ inline unsigned short f2bf(float f) {   // round-to-nearest-even bf16
    unsigned int u = __float_as_uint(f);
    u += 0x7FFFu + ((u >> 16) & 1u);
    return (unsigned short)(u >> 16);
}
__device__ inline float bflo(unsigned int v) { return __uint_as_float(v << 16); }
__device__ inline float bfhi(unsigned int v) { return __uint_as_float(v & 0xFFFF0000u); }

// ---- transpose the 64x64 weight matrices (3 lin layers + final fc) ----
__global__ __launch_bounds__(256) void k_transpose(
    const float* __restrict__ linw, const float* __restrict__ fcw,
    float* __restrict__ wt)
{
    const float* src = (blockIdx.x < 3) ? (linw + blockIdx.x * 4096) : fcw;
    float* dst = wt + blockIdx.x * 4096;
    for (int i = threadIdx.x; i < 4096; i += 256)
        dst[(i & 63) * 64 + (i >> 6)] = src[i];   // wt[k][j] = w[j][k]
}

// ---- x (fp32) -> bf16 shadow ----
__global__ __launch_bounds__(256) void k_cvt(
    const float* __restrict__ x, unsigned short* __restrict__ hb)
{
    int stride = gridDim.x * blockDim.x;
    const float4* x4 = (const float4*)x;
    ushort4* hb4 = (ushort4*)hb;
    for (int i = blockIdx.x * blockDim.x + threadIdx.x; i < NN * 16; i += stride) {
        float4 v = x4[i];
        hb4[i] = make_ushort4(f2bf(v.x), f2bf(v.y), f2bf(v.z), f2bf(v.w));
    }
}

// ---- histogram of dst degrees ----
__global__ __launch_bounds__(256) void k_hist(
    const int* __restrict__ ei, int* __restrict__ deg)
{
    int stride = gridDim.x * blockDim.x;
    for (int e = blockIdx.x * blockDim.x + threadIdx.x; e < NE; e += stride)
        atomicAdd(&deg[ei[NE + e]], 1);
}

// ---- hierarchical exclusive scan: 1024-elem chunks ----
__global__ __launch_bounds__(256) void k_scan1(
    const int* __restrict__ deg, int* __restrict__ base, int* __restrict__ csum)
{
    __shared__ int lds[256];
    int tid = threadIdx.x;
    int i0 = blockIdx.x * 1024 + tid * 4;
    int d[4];
    #pragma unroll
    for (int k = 0; k < 4; ++k) d[k] = (i0 + k < NN) ? deg[i0 + k] : 0;
    int s = d[0] + d[1] + d[2] + d[3];
    lds[tid] = s;
    __syncthreads();
    for (int off = 1; off < 256; off <<= 1) {
        int add = (tid >= off) ? lds[tid - off] : 0;
        __syncthreads();
        lds[tid] += add;
        __syncthreads();
    }
    int excl = lds[tid] - s;
    if (i0 + 0 < NN) base[i0 + 0] = excl;
    if (i0 + 1 < NN) base[i0 + 1] = excl + d[0];
    if (i0 + 2 < NN) base[i0 + 2] = excl + d[0] + d[1];
    if (i0 + 3 < NN) base[i0 + 3] = excl + d[0] + d[1] + d[2];
    if (tid == 255) csum[blockIdx.x] = lds[255];
}

__global__ __launch_bounds__(128) void k_scan2(
    const int* __restrict__ csum, int* __restrict__ coff)
{
    __shared__ int lds[128];
    int tid = threadIdx.x;
    int v = (tid < NCHUNK) ? csum[tid] : 0;
    lds[tid] = v;
    __syncthreads();
    for (int off = 1; off < 128; off <<= 1) {
        int add = (tid >= off) ? lds[tid - off] : 0;
        __syncthreads();
        lds[tid] += add;
        __syncthreads();
    }
    coff[tid] = lds[tid] - v;   // exclusive
}

__global__ __launch_bounds__(256) void k_scan3(
    int* __restrict__ base, int* __restrict__ cursor, const int* __restrict__ coff)
{
    int off = coff[blockIdx.x];
    int i0 = blockIdx.x * 1024 + threadIdx.x * 4;
    #pragma unroll
    for (int k = 0; k < 4; ++k)
        if (i0 + k < NN) {
            int b = base[i0 + k] + off;
            base[i0 + k] = b;
            cursor[i0 + k] = b;
        }
    if (blockIdx.x == 0 && threadIdx.x == 0) base[NN] = NE;
}

// ---- fill CSR slots: pk[slot] = {src, w0, w1, w2} (softplus fused here) ----
__global__ __launch_bounds__(256) void k_fill(
    const int* __restrict__ ei, const float* __restrict__ ea,
    const float* __restrict__ mw, const float* __restrict__ mb,
    int* __restrict__ cursor, float4* __restrict__ pk)
{
    float wl[3][8], bl[3];
    #pragma unroll
    for (int l = 0; l < 3; ++l) {
        bl[l] = mb[l];
        #pragma unroll
        for (int k = 0; k < 8; ++k) wl[l][k] = mw[l * 8 + k];
    }
    int stride = gridDim.x * blockDim.x;
    const float4* ea4 = (const float4*)ea;
    for (int e = blockIdx.x * blockDim.x + threadIdx.x; e < NE; e += stride) {
        float4 a0 = ea4[2 * e], a1 = ea4[2 * e + 1];
        float av[8] = {a0.x, a0.y, a0.z, a0.w, a1.x, a1.y, a1.z, a1.w};
        float w[3];
        #pragma unroll
        for (int l = 0; l < 3; ++l) {
            float xx = bl[l];
            #pragma unroll
            for (int k = 0; k < 8; ++k) xx += av[k] * wl[l][k];
            w[l] = fmaxf(xx, 0.f) + log1pf(expf(-fabsf(xx)));  // stable softplus
        }
        int src = ei[e], dst = ei[NE + e];
        int slot = atomicAdd(&cursor[dst], 1);
        pk[slot] = make_float4(__int_as_float(src), w[0], w[1], w[2]);
    }
}

// ---- atomic-free aggregation: 16 lanes/node (4 nodes per wave), bf16 gathers
// aout[n] = sum_e w_e * hb[src_e] - (sum_e w_e) * h[n]   (fold term in fp32)
template<int L>
__global__ __launch_bounds__(256) void k_agg(
    const int* __restrict__ base, const float4* __restrict__ pk,
    const unsigned short* __restrict__ hb, const float* __restrict__ h,
    float* __restrict__ aout)
{
    int lane = threadIdx.x & 63;
    int sub = lane & 15;     // channel group: channels [4*sub, 4*sub+4)
    int g = lane >> 4;       // node slot within wave (0..3)
    int wid = (blockIdx.x * blockDim.x + threadIdx.x) >> 6;
    int nwave = (gridDim.x * blockDim.x) >> 6;
    for (int n = wid * 4 + g; n < NN; n += nwave * 4) {
        int s = base[n], e2 = base[n + 1];
        float a0 = 0.f, a1 = 0.f, a2 = 0.f, a3 = 0.f, wsn = 0.f;
        int sl = s;
        for (; sl + 4 <= e2; sl += 4) {
            float4 p0 = pk[sl], p1 = pk[sl + 1], p2 = pk[sl + 2], p3 = pk[sl + 3];
            uint2 v0 = *(const uint2*)(hb + ((size_t)__float_as_int(p0.x) << 6) + sub * 4);
            uint2 v1 = *(const uint2*)(hb + ((size_t)__float_as_int(p1.x) << 6) + sub * 4);
            uint2 v2 = *(const uint2*)(hb + ((size_t)__float_as_int(p2.x) << 6) + sub * 4);
            uint2 v3 = *(const uint2*)(hb + ((size_t)__float_as_int(p3.x) << 6) + sub * 4);
            float w0 = (L == 0) ? p0.y : (L == 1) ? p0.z : p0.w;
            float w1 = (L == 0) ? p1.y : (L == 1) ? p1.z : p1.w;
            float w2 = (L == 0) ? p2.y : (L == 1) ? p2.z : p2.w;
            float w3 = (L == 0) ? p3.y : (L == 1) ? p3.z : p3.w;
            a0 += w0 * bflo(v0.x); a1 += w0 * bfhi(v0.x); a2 += w0 * bflo(v0.y); a3 += w0 * bfhi(v0.y);
            a0 += w1 * bflo(v1.x); a1 += w1 * bfhi(v1.x); a2 += w1 * bflo(v1.y); a3 += w1 * bfhi(v1.y);
            a0 += w2 * bflo(v2.x); a1 += w2 * bfhi(v2.x); a2 += w2 * bflo(v2.y); a3 += w2 * bfhi(v2.y);
            a0 += w3 * bflo(v3.x); a1 += w3 * bfhi(v3.x); a2 += w3 * bflo(v3.y); a3 += w3 * bfhi(v3.y);
            wsn += w0 + w1 + w2 + w3;
        }
        for (; sl < e2; ++sl) {
            float4 p = pk[sl];
            uint2 v = *(const uint2*)(hb + ((size_t)__float_as_int(p.x) << 6) + sub * 4);
            float w = (L == 0) ? p.y : (L == 1) ? p.z : p.w;
            a0 += w * bflo(v.x); a1 += w * bfhi(v.x); a2 += w * bflo(v.y); a3 += w * bfhi(v.y);
            wsn += w;
        }
        float4 hv = *(const float4*)(h + (size_t)n * 64 + sub * 4);
        float4 o = {a0 - wsn * hv.x, a1 - wsn * hv.y, a2 - wsn * hv.z, a3 - wsn * hv.w};
        *(float4*)(aout + (size_t)n * 64 + sub * 4) = o;
    }
}

// ---- fused: y = relu(a @ W^T + b) ; LN ; +residual ; emit fp32 + bf16 shadow ----
// NOTE: hout may alias a (per-row in-place) -> no __restrict on those two.
__global__ __launch_bounds__(256) void k_node(
    const float* a, const float* __restrict__ hin, float* hout,
    unsigned short* __restrict__ hbout,
    const float* __restrict__ wt, const float* __restrict__ bias,
    const float* __restrict__ gamma, const float* __restrict__ beta)
{
    int n0 = blockIdx.x * blockDim.x + threadIdx.x;
    int stride = gridDim.x * blockDim.x;
    const float4* a4 = (const float4*)a;
    const float4* hin4 = (const float4*)hin;
    float4* ho4 = (float4*)hout;
    ushort4* hb4 = (ushort4*)hbout;
    for (int n = n0; n < NN; n += stride) {
        float y[64];
        #pragma unroll
        for (int j = 0; j < 64; ++j) y[j] = bias[j];
        #pragma unroll 2
        for (int k4 = 0; k4 < 16; ++k4) {
            float4 gg = a4[n * 16 + k4];
            float av[4] = {gg.x, gg.y, gg.z, gg.w};
            #pragma unroll
            for (int kk = 0; kk < 4; ++kk) {
                const float* wr = wt + (k4 * 4 + kk) * 64;
                #pragma unroll
                for (int j = 0; j < 64; ++j) y[j] += av[kk] * wr[j];
            }
        }
        float s = 0.f, s2 = 0.f;
        #pragma unroll
        for (int j = 0; j < 64; ++j) {
            y[j] = fmaxf(y[j], 0.f);
            s += y[j]; s2 += y[j] * y[j];
        }
        float mu = s * (1.f / 64.f);
        float var = s2 * (1.f / 64.f) - mu * mu;
        float inv = rsqrtf(var + 1e-5f);
        #pragma unroll
        for (int j4 = 0; j4 < 16; ++j4) {
            float4 hh = hin4[n * 16 + j4];
            float4 o;
            o.x = (y[4*j4+0] - mu) * inv * gamma[4*j4+0] + beta[4*j4+0] + hh.x;
            o.y = (y[4*j4+1] - mu) * inv * gamma[4*j4+1] + beta[4*j4+1] + hh.y;
            o.z = (y[4*j4+2] - mu) * inv * gamma[4*j4+2] + beta[4*j4+2] + hh.z;
            o.w = (y[4*j4+3] - mu) * inv * gamma[4*j4+3] + beta[4*j4+3] + hh.w;
            ho4[n * 16 + j4] = o;
            if (hbout)
                hb4[n * 16 + j4] = make_ushort4(f2bf(o.x), f2bf(o.y), f2bf(o.z), f2bf(o.w));
        }
    }
}

// ---- final fc: out = h @ fc_w^T + fc_b ----
__global__ __launch_bounds__(256) void k_fc(
    const float* __restrict__ hin, float* __restrict__ out,
    const float* __restrict__ wt, const float* __restrict__ bias)
{
    int n0 = blockIdx.x * blockDim.x + threadIdx.x;
    int stride = gridDim.x * blockDim.x;
    const float4* hin4 = (const float4*)hin;
    float4* o4 = (float4*)out;
    for (int n = n0; n < NN; n += stride) {
        float y[64];
        #pragma unroll
        for (int j = 0; j < 64; ++j) y[j] = bias[j];
        #pragma unroll 2
        for (int k4 = 0; k4 < 16; ++k4) {
            float4 hh = hin4[n * 16 + k4];
            float hv[4] = {hh.x, hh.y, hh.z, hh.w};
            #pragma unroll
            for (int kk = 0; kk < 4; ++kk) {
                const float* wr = wt + (k4 * 4 + kk) * 64;
                #pragma unroll
                for (int j = 0; j < 64; ++j) y[j] += hv[kk] * wr[j];
            }
        }
        #pragma unroll
        for (int j4 = 0; j4 < 16; ++j4) {
            float4 o = {y[4*j4], y[4*j4+1], y[4*j4+2], y[4*j4+3]};
            o4[n * 16 + j4] = o;
        }
    }
}

extern "C" void kernel_launch(void* const* d_in, const int* in_sizes, int n_in,
                              void* d_out, int out_size, void* d_ws, size_t ws_size,
                              hipStream_t stream)
{
    const float* x     = (const float*)d_in[0];
    const int*   ei    = (const int*)d_in[1];
    const float* ea    = (const float*)d_in[2];
    const float* linw  = (const float*)d_in[3];
    const float* linb  = (const float*)d_in[4];
    const float* mw    = (const float*)d_in[5];
    const float* mb    = (const float*)d_in[6];
    const float* gamma = (const float*)d_in[7];
    const float* beta  = (const float*)d_in[8];
    const float* fcw   = (const float*)d_in[9];
    const float* fcb   = (const float*)d_in[10];
    float* out = (float*)d_out;

    // workspace layout (~117 MB)
    float*  A    = (float*)d_ws;                   // NN*64
    float*  C    = A + (size_t)NN * 64;            // NN*64
    float4* pk   = (float4*)(C + (size_t)NN * 64); // NE float4
    float*  wt   = (float*)(pk + (size_t)NE);      // 4*4096
    int*    deg  = (int*)(wt + 4 * 4096);          // NN
    int*    base = deg + NN;                       // NN+1
    int*    cur  = base + NN + 1;                  // NN
    int*    csum = cur + NN;                       // 128
    int*    coff = csum + 128;                     // 128
    unsigned short* hb = (unsigned short*)(coff + 128);  // NN*64 bf16

    k_transpose<<<4, 256, 0, stream>>>(linw, fcw, wt);
    k_cvt<<<2048, 256, 0, stream>>>(x, hb);
    hipMemsetAsync(deg, 0, NN * sizeof(int), stream);
    k_hist<<<2048, 256, 0, stream>>>(ei, deg);
    k_scan1<<<NCHUNK, 256, 0, stream>>>(deg, base, csum);
    k_scan2<<<1, 128, 0, stream>>>(csum, coff);
    k_scan3<<<NCHUNK, 256, 0, stream>>>(base, cur, coff);
    k_fill<<<2048, 256, 0, stream>>>(ei, ea, mw, mb, cur, pk);

    // l0: x -> C ; l1: C -> A ; l2: A -> C   (hb holds bf16 of current h)
    k_agg<0><<<6250, 256, 0, stream>>>(base, pk, hb, x, C);
    k_node<<<512, 256, 0, stream>>>(C, x, C, hb, wt + 0 * 4096, linb + 0 * 64,
                                    gamma + 0 * 64, beta + 0 * 64);
    k_agg<1><<<6250, 256, 0, stream>>>(base, pk, hb, C, A);
    k_node<<<512, 256, 0, stream>>>(A, C, A, hb, wt + 1 * 4096, linb + 1 * 64,
                                    gamma + 1 * 64, beta + 1 * 64);
    k_agg<2><<<6250, 256, 0, stream>>>(base, pk, hb, A, C);
    k_node<<<512, 256, 0, stream>>>(C, A, C, (unsigned short*)nullptr,
                                    wt + 2 * 4096, linb + 2 * 64,
                                    gamma + 2 * 64, beta + 2 * 64);

    k_fc<<<512, 256, 0, stream>>>(C, out, wt + 3 * 4096, fcb);
}

// Round 7
// 901.918 us; speedup vs baseline: 3.1517x; 1.1132x over previous
//
#include <hip/hip_runtime.h>

#define NN 100000
#define NE 3200000
#define NCHUNK 98   // ceil(NN / 1024)

__device__ inline unsigned short f2bf(float f) {   // round-to-nearest-even bf16
    unsigned int u = __float_as_uint(f);
    u += 0x7FFFu + ((u >> 16) & 1u);
    return (unsigned short)(u >> 16);
}
__device__ inline float bflo(unsigned int v) { return __uint_as_float(v << 16); }
__device__ inline float bfhi(unsigned int v) { return __uint_as_float(v & 0xFFFF0000u); }

// ---- transpose the 64x64 weight matrices (3 lin layers + final fc) ----
__global__ __launch_bounds__(256) void k_transpose(
    const float* __restrict__ linw, const float* __restrict__ fcw,
    float* __restrict__ wt)
{
    const float* src = (blockIdx.x < 3) ? (linw + blockIdx.x * 4096) : fcw;
    float* dst = wt + blockIdx.x * 4096;
    for (int i = threadIdx.x; i < 4096; i += 256)
        dst[(i & 63) * 64 + (i >> 6)] = src[i];   // wt[k][j] = w[j][k]
}

// ---- x (fp32) -> bf16 shadow ----
__global__ __launch_bounds__(256) void k_cvt(
    const float* __restrict__ x, unsigned short* __restrict__ hb)
{
    int stride = gridDim.x * blockDim.x;
    const float4* x4 = (const float4*)x;
    ushort4* hb4 = (ushort4*)hb;
    for (int i = blockIdx.x * blockDim.x + threadIdx.x; i < NN * 16; i += stride) {
        float4 v = x4[i];
        hb4[i] = make_ushort4(f2bf(v.x), f2bf(v.y), f2bf(v.z), f2bf(v.w));
    }
}

// ---- histogram of dst degrees ----
__global__ __launch_bounds__(256) void k_hist(
    const int* __restrict__ ei, int* __restrict__ deg)
{
    int stride = gridDim.x * blockDim.x;
    for (int e = blockIdx.x * blockDim.x + threadIdx.x; e < NE; e += stride)
        atomicAdd(&deg[ei[NE + e]], 1);
}

// ---- hierarchical exclusive scan: 1024-elem chunks ----
__global__ __launch_bounds__(256) void k_scan1(
    const int* __restrict__ deg, int* __restrict__ base, int* __restrict__ csum)
{
    __shared__ int lds[256];
    int tid = threadIdx.x;
    int i0 = blockIdx.x * 1024 + tid * 4;
    int d[4];
    #pragma unroll
    for (int k = 0; k < 4; ++k) d[k] = (i0 + k < NN) ? deg[i0 + k] : 0;
    int s = d[0] + d[1] + d[2] + d[3];
    lds[tid] = s;
    __syncthreads();
    for (int off = 1; off < 256; off <<= 1) {
        int add = (tid >= off) ? lds[tid - off] : 0;
        __syncthreads();
        lds[tid] += add;
        __syncthreads();
    }
    int excl = lds[tid] - s;
    if (i0 + 0 < NN) base[i0 + 0] = excl;
    if (i0 + 1 < NN) base[i0 + 1] = excl + d[0];
    if (i0 + 2 < NN) base[i0 + 2] = excl + d[0] + d[1];
    if (i0 + 3 < NN) base[i0 + 3] = excl + d[0] + d[1] + d[2];
    if (tid == 255) csum[blockIdx.x] = lds[255];
}

__global__ __launch_bounds__(128) void k_scan2(
    const int* __restrict__ csum, int* __restrict__ coff)
{
    __shared__ int lds[128];
    int tid = threadIdx.x;
    int v = (tid < NCHUNK) ? csum[tid] : 0;
    lds[tid] = v;
    __syncthreads();
    for (int off = 1; off < 128; off <<= 1) {
        int add = (tid >= off) ? lds[tid - off] : 0;
        __syncthreads();
        lds[tid] += add;
        __syncthreads();
    }
    coff[tid] = lds[tid] - v;   // exclusive
}

__global__ __launch_bounds__(256) void k_scan3(
    int* __restrict__ base, int* __restrict__ cursor, const int* __restrict__ coff)
{
    int off = coff[blockIdx.x];
    int i0 = blockIdx.x * 1024 + threadIdx.x * 4;
    #pragma unroll
    for (int k = 0; k < 4; ++k)
        if (i0 + k < NN) {
            int b = base[i0 + k] + off;
            base[i0 + k] = b;
            cursor[i0 + k] = b;
        }
    if (blockIdx.x == 0 && threadIdx.x == 0) base[NN] = NE;
}

// ---- fill CSR slots: 8B record {src(17b) | w0(15b)<<17 ; w1(15b) | w2(15b)<<15}
//      w_l = softplus(...) >= 0 -> bf16 sign bit always 0 -> 15 bits exact bf16.
//      float reconstruction of a 15-bit wb is (wb << 16). ----
__global__ __launch_bounds__(256) void k_fill(
    const int* __restrict__ ei, const float* __restrict__ ea,
    const float* __restrict__ mw, const float* __restrict__ mb,
    int* __restrict__ cursor, uint2* __restrict__ pk)
{
    float wl[3][8], bl[3];
    #pragma unroll
    for (int l = 0; l < 3; ++l) {
        bl[l] = mb[l];
        #pragma unroll
        for (int k = 0; k < 8; ++k) wl[l][k] = mw[l * 8 + k];
    }
    int stride = gridDim.x * blockDim.x;
    const float4* ea4 = (const float4*)ea;
    for (int e = blockIdx.x * blockDim.x + threadIdx.x; e < NE; e += stride) {
        float4 a0 = ea4[2 * e], a1 = ea4[2 * e + 1];
        float av[8] = {a0.x, a0.y, a0.z, a0.w, a1.x, a1.y, a1.z, a1.w};
        unsigned int wb[3];
        #pragma unroll
        for (int l = 0; l < 3; ++l) {
            float xx = bl[l];
            #pragma unroll
            for (int k = 0; k < 8; ++k) xx += av[k] * wl[l][k];
            float sp = fmaxf(xx, 0.f) + log1pf(expf(-fabsf(xx)));  // stable softplus
            wb[l] = f2bf(sp) & 0x7FFFu;
        }
        int src = ei[e], dst = ei[NE + e];
        int slot = atomicAdd(&cursor[dst], 1);
        uint2 rec;
        rec.x = (unsigned int)src | (wb[0] << 17);
        rec.y = wb[1] | (wb[2] << 15);
        pk[slot] = rec;
    }
}

// ---- per-layer weight decode: float(wb) = wb << 16 (sign-free bf16) ----
template<int L>
__device__ inline float dec_w(uint2 p) {
    if (L == 0) return __uint_as_float((p.x >> 17) << 16);
    if (L == 1) return __uint_as_float((p.y & 0x7FFFu) << 16);
    return __uint_as_float((p.y >> 15) << 16);
}

// ---- atomic-free aggregation: 8 lanes/node (8 nodes per wave), uint4 bf16 gathers
// aout[n] = sum_e w_e * hb[src_e] - (sum_e w_e) * h[n]   (fold term in fp32)
template<int L>
__global__ __launch_bounds__(256) void k_agg(
    const int* __restrict__ base, const uint2* __restrict__ pk,
    const unsigned short* __restrict__ hb, const float* __restrict__ h,
    float* __restrict__ aout)
{
    int lane = threadIdx.x & 63;
    int sub = lane & 7;      // channel group: channels [8*sub, 8*sub+8)
    int g = lane >> 3;       // node slot within wave (0..7)
    int wid = (blockIdx.x * blockDim.x + threadIdx.x) >> 6;
    int nwave = (gridDim.x * blockDim.x) >> 6;
    for (int n = wid * 8 + g; n < NN; n += nwave * 8) {
        int s = base[n], e2 = base[n + 1];
        float a0 = 0.f, a1 = 0.f, a2 = 0.f, a3 = 0.f;
        float a4 = 0.f, a5 = 0.f, a6 = 0.f, a7 = 0.f, wsn = 0.f;
        int sl = s;
        for (; sl + 4 <= e2; sl += 4) {
            uint2 p0 = pk[sl], p1 = pk[sl + 1], p2 = pk[sl + 2], p3 = pk[sl + 3];
            uint4 v0 = *(const uint4*)(hb + (((size_t)(p0.x & 0x1FFFF)) << 6) + (sub << 3));
            uint4 v1 = *(const uint4*)(hb + (((size_t)(p1.x & 0x1FFFF)) << 6) + (sub << 3));
            uint4 v2 = *(const uint4*)(hb + (((size_t)(p2.x & 0x1FFFF)) << 6) + (sub << 3));
            uint4 v3 = *(const uint4*)(hb + (((size_t)(p3.x & 0x1FFFF)) << 6) + (sub << 3));
            float w0 = dec_w<L>(p0), w1 = dec_w<L>(p1), w2 = dec_w<L>(p2), w3 = dec_w<L>(p3);
            a0 += w0 * bflo(v0.x); a1 += w0 * bfhi(v0.x); a2 += w0 * bflo(v0.y); a3 += w0 * bfhi(v0.y);
            a4 += w0 * bflo(v0.z); a5 += w0 * bfhi(v0.z); a6 += w0 * bflo(v0.w); a7 += w0 * bfhi(v0.w);
            a0 += w1 * bflo(v1.x); a1 += w1 * bfhi(v1.x); a2 += w1 * bflo(v1.y); a3 += w1 * bfhi(v1.y);
            a4 += w1 * bflo(v1.z); a5 += w1 * bfhi(v1.z); a6 += w1 * bflo(v1.w); a7 += w1 * bfhi(v1.w);
            a0 += w2 * bflo(v2.x); a1 += w2 * bfhi(v2.x); a2 += w2 * bflo(v2.y); a3 += w2 * bfhi(v2.y);
            a4 += w2 * bflo(v2.z); a5 += w2 * bfhi(v2.z); a6 += w2 * bflo(v2.w); a7 += w2 * bfhi(v2.w);
            a0 += w3 * bflo(v3.x); a1 += w3 * bfhi(v3.x); a2 += w3 * bflo(v3.y); a3 += w3 * bfhi(v3.y);
            a4 += w3 * bflo(v3.z); a5 += w3 * bfhi(v3.z); a6 += w3 * bflo(v3.w); a7 += w3 * bfhi(v3.w);
            wsn += w0 + w1 + w2 + w3;
        }
        for (; sl < e2; ++sl) {
            uint2 p = pk[sl];
            uint4 v = *(const uint4*)(hb + (((size_t)(p.x & 0x1FFFF)) << 6) + (sub << 3));
            float w = dec_w<L>(p);
            a0 += w * bflo(v.x); a1 += w * bfhi(v.x); a2 += w * bflo(v.y); a3 += w * bfhi(v.y);
            a4 += w * bflo(v.z); a5 += w * bfhi(v.z); a6 += w * bflo(v.w); a7 += w * bfhi(v.w);
            wsn += w;
        }
        const float* hrow = h + (size_t)n * 64 + sub * 8;
        float4 h0 = *(const float4*)hrow;
        float4 h1 = *(const float4*)(hrow + 4);
        float* orow = aout + (size_t)n * 64 + sub * 8;
        float4 o0 = {a0 - wsn * h0.x, a1 - wsn * h0.y, a2 - wsn * h0.z, a3 - wsn * h0.w};
        float4 o1 = {a4 - wsn * h1.x, a5 - wsn * h1.y, a6 - wsn * h1.z, a7 - wsn * h1.w};
        *(float4*)orow = o0;
        *(float4*)(orow + 4) = o1;
    }
}

// ---- fused: y = relu(a @ W^T + b) ; LN ; +residual ; emit fp32 + bf16 shadow ----
// NOTE: hout may alias a (per-row in-place) -> no __restrict on those two.
__global__ __launch_bounds__(256) void k_node(
    const float* a, const float* __restrict__ hin, float* hout,
    unsigned short* __restrict__ hbout,
    const float* __restrict__ wt, const float* __restrict__ bias,
    const float* __restrict__ gamma, const float* __restrict__ beta)
{
    int n0 = blockIdx.x * blockDim.x + threadIdx.x;
    int stride = gridDim.x * blockDim.x;
    const float4* a4 = (const float4*)a;
    const float4* hin4 = (const float4*)hin;
    float4* ho4 = (float4*)hout;
    ushort4* hb4 = (ushort4*)hbout;
    for (int n = n0; n < NN; n += stride) {
        float y[64];
        #pragma unroll
        for (int j = 0; j < 64; ++j) y[j] = bias[j];
        #pragma unroll 2
        for (int k4 = 0; k4 < 16; ++k4) {
            float4 gg = a4[n * 16 + k4];
            float av[4] = {gg.x, gg.y, gg.z, gg.w};
            #pragma unroll
            for (int kk = 0; kk < 4; ++kk) {
                const float* wr = wt + (k4 * 4 + kk) * 64;
                #pragma unroll
                for (int j = 0; j < 64; ++j) y[j] += av[kk] * wr[j];
            }
        }
        float s = 0.f, s2 = 0.f;
        #pragma unroll
        for (int j = 0; j < 64; ++j) {
            y[j] = fmaxf(y[j], 0.f);
            s += y[j]; s2 += y[j] * y[j];
        }
        float mu = s * (1.f / 64.f);
        float var = s2 * (1.f / 64.f) - mu * mu;
        float inv = rsqrtf(var + 1e-5f);
        #pragma unroll
        for (int j4 = 0; j4 < 16; ++j4) {
            float4 hh = hin4[n * 16 + j4];
            float4 o;
            o.x = (y[4*j4+0] - mu) * inv * gamma[4*j4+0] + beta[4*j4+0] + hh.x;
            o.y = (y[4*j4+1] - mu) * inv * gamma[4*j4+1] + beta[4*j4+1] + hh.y;
            o.z = (y[4*j4+2] - mu) * inv * gamma[4*j4+2] + beta[4*j4+2] + hh.z;
            o.w = (y[4*j4+3] - mu) * inv * gamma[4*j4+3] + beta[4*j4+3] + hh.w;
            ho4[n * 16 + j4] = o;
            if (hbout)
                hb4[n * 16 + j4] = make_ushort4(f2bf(o.x), f2bf(o.y), f2bf(o.z), f2bf(o.w));
        }
    }
}

// ---- final fc: out = h @ fc_w^T + fc_b ----
__global__ __launch_bounds__(256) void k_fc(
    const float* __restrict__ hin, float* __restrict__ out,
    const float* __restrict__ wt, const float* __restrict__ bias)
{
    int n0 = blockIdx.x * blockDim.x + threadIdx.x;
    int stride = gridDim.x * blockDim.x;
    const float4* hin4 = (const float4*)hin;
    float4* o4 = (float4*)out;
    for (int n = n0; n < NN; n += stride) {
        float y[64];
        #pragma unroll
        for (int j = 0; j < 64; ++j) y[j] = bias[j];
        #pragma unroll 2
        for (int k4 = 0; k4 < 16; ++k4) {
            float4 hh = hin4[n * 16 + k4];
            float hv[4] = {hh.x, hh.y, hh.z, hh.w};
            #pragma unroll
            for (int kk = 0; kk < 4; ++kk) {
                const float* wr = wt + (k4 * 4 + kk) * 64;
                #pragma unroll
                for (int j = 0; j < 64; ++j) y[j] += hv[kk] * wr[j];
            }
        }
        #pragma unroll
        for (int j4 = 0; j4 < 16; ++j4) {
            float4 o = {y[4*j4], y[4*j4+1], y[4*j4+2], y[4*j4+3]};
            o4[n * 16 + j4] = o;
        }
    }
}

extern "C" void kernel_launch(void* const* d_in, const int* in_sizes, int n_in,
                              void* d_out, int out_size, void* d_ws, size_t ws_size,
                              hipStream_t stream)
{
    const float* x     = (const float*)d_in[0];
    const int*   ei    = (const int*)d_in[1];
    const float* ea    = (const float*)d_in[2];
    const float* linw  = (const float*)d_in[3];
    const float* linb  = (const float*)d_in[4];
    const float* mw    = (const float*)d_in[5];
    const float* mb    = (const float*)d_in[6];
    const float* gamma = (const float*)d_in[7];
    const float* beta  = (const float*)d_in[8];
    const float* fcw   = (const float*)d_in[9];
    const float* fcb   = (const float*)d_in[10];
    float* out = (float*)d_out;

    // workspace layout (~91 MB), hb 16B-aligned for uint4 gathers
    float*  A    = (float*)d_ws;                        // NN*64 f32   @ 0
    float*  C    = A + (size_t)NN * 64;                 // NN*64 f32   @ 25.6MB
    uint2*  pk   = (uint2*)(C + (size_t)NN * 64);       // NE uint2    @ 51.2MB
    unsigned short* hb = (unsigned short*)(pk + NE);    // NN*64 bf16  @ 76.8MB (16B-aligned)
    float*  wt   = (float*)(hb + (size_t)NN * 64);      // 4*4096 f32
    int*    deg  = (int*)(wt + 4 * 4096);               // NN
    int*    base = deg + NN;                            // NN+1
    int*    cur  = base + NN + 1;                       // NN
    int*    csum = cur + NN;                            // 128
    int*    coff = csum + 128;                          // 128

    k_transpose<<<4, 256, 0, stream>>>(linw, fcw, wt);
    k_cvt<<<2048, 256, 0, stream>>>(x, hb);
    hipMemsetAsync(deg, 0, NN * sizeof(int), stream);
    k_hist<<<2048, 256, 0, stream>>>(ei, deg);
    k_scan1<<<NCHUNK, 256, 0, stream>>>(deg, base, csum);
    k_scan2<<<1, 128, 0, stream>>>(csum, coff);
    k_scan3<<<NCHUNK, 256, 0, stream>>>(base, cur, coff);
    k_fill<<<2048, 256, 0, stream>>>(ei, ea, mw, mb, cur, pk);

    // l0: x -> C ; l1: C -> A ; l2: A -> C   (hb holds bf16 of current h)
    k_agg<0><<<3125, 256, 0, stream>>>(base, pk, hb, x, C);
    k_node<<<512, 256, 0, stream>>>(C, x, C, hb, wt + 0 * 4096, linb + 0 * 64,
                                    gamma + 0 * 64, beta + 0 * 64);
    k_agg<1><<<3125, 256, 0, stream>>>(base, pk, hb, C, A);
    k_node<<<512, 256, 0, stream>>>(A, C, A, hb, wt + 1 * 4096, linb + 1 * 64,
                                    gamma + 1 * 64, beta + 1 * 64);
    k_agg<2><<<3125, 256, 0, stream>>>(base, pk, hb, A, C);
    k_node<<<512, 256, 0, stream>>>(C, A, C, (unsigned short*)nullptr,
                                    wt + 2 * 4096, linb + 2 * 64,
                                    gamma + 2 * 64, beta + 2 * 64);

    k_fc<<<512, 256, 0, stream>>>(C, out, wt + 3 * 4096, fcb);
}

// Round 8
// 878.367 us; speedup vs baseline: 3.2362x; 1.0268x over previous
//
#include <hip/hip_runtime.h>

#define NN 100000
#define NE 3200000
#define NBKT 391            // ceil(NN / 256) buckets of 256 nodes
#define NBLK 256            // partition blocks (fixed edge ranges)
#define EPB (NE / NBLK)     // 12500 edges per block
#define GH_N (NBKT * NBLK)  // 100096

__device__ inline unsigned short f2bf(float f) {   // round-to-nearest-even bf16
    unsigned int u = __float_as_uint(f);
    u += 0x7FFFu + ((u >> 16) & 1u);
    return (unsigned short)(u >> 16);
}
__device__ inline float bflo(unsigned int v) { return __uint_as_float(v << 16); }
__device__ inline float bfhi(unsigned int v) { return __uint_as_float(v & 0xFFFF0000u); }

// ---- transpose the 64x64 weight matrices (3 lin layers + final fc) ----
__global__ __launch_bounds__(256) void k_transpose(
    const float* __restrict__ linw, const float* __restrict__ fcw,
    float* __restrict__ wt)
{
    const float* src = (blockIdx.x < 3) ? (linw + blockIdx.x * 4096) : fcw;
    float* dst = wt + blockIdx.x * 4096;
    for (int i = threadIdx.x; i < 4096; i += 256)
        dst[(i & 63) * 64 + (i >> 6)] = src[i];   // wt[k][j] = w[j][k]
}

// ---- x (fp32) -> bf16 shadow ----
__global__ __launch_bounds__(256) void k_cvt(
    const float* __restrict__ x, unsigned short* __restrict__ hb)
{
    int stride = gridDim.x * blockDim.x;
    const float4* x4 = (const float4*)x;
    ushort4* hb4 = (ushort4*)hb;
    for (int i = blockIdx.x * blockDim.x + threadIdx.x; i < NN * 16; i += stride) {
        float4 v = x4[i];
        hb4[i] = make_ushort4(f2bf(v.x), f2bf(v.y), f2bf(v.z), f2bf(v.w));
    }
}

// ---- merged histograms: per-node degree (global) + per-(bucket,block) (LDS) ----
__global__ __launch_bounds__(1024) void k_hist2(
    const int* __restrict__ ei, int* __restrict__ deg, int* __restrict__ gh)
{
    __shared__ int lh[NBKT];
    for (int t = threadIdx.x; t < NBKT; t += 1024) lh[t] = 0;
    __syncthreads();
    int bi = blockIdx.x;
    int e1 = bi * EPB + EPB;
    for (int e = bi * EPB + threadIdx.x; e < e1; e += 1024) {
        int dst = ei[NE + e];
        atomicAdd(&deg[dst], 1);
        atomicAdd(&lh[dst >> 8], 1);
    }
    __syncthreads();
    for (int t = threadIdx.x; t < NBKT; t += 1024)
        gh[t * NBLK + bi] = lh[t];
}

// ---- hierarchical exclusive scan over n elements (n <= 128*1024) ----
__global__ __launch_bounds__(256) void k_scan1(
    const int* __restrict__ in, int* __restrict__ out, int* __restrict__ csum, int n)
{
    __shared__ int lds[256];
    int tid = threadIdx.x;
    int i0 = blockIdx.x * 1024 + tid * 4;
    int d[4];
    #pragma unroll
    for (int k = 0; k < 4; ++k) d[k] = (i0 + k < n) ? in[i0 + k] : 0;
    int s = d[0] + d[1] + d[2] + d[3];
    lds[tid] = s;
    __syncthreads();
    for (int off = 1; off < 256; off <<= 1) {
        int add = (tid >= off) ? lds[tid - off] : 0;
        __syncthreads();
        lds[tid] += add;
        __syncthreads();
    }
    int excl = lds[tid] - s;
    if (i0 + 0 < n) out[i0 + 0] = excl;
    if (i0 + 1 < n) out[i0 + 1] = excl + d[0];
    if (i0 + 2 < n) out[i0 + 2] = excl + d[0] + d[1];
    if (i0 + 3 < n) out[i0 + 3] = excl + d[0] + d[1] + d[2];
    if (tid == 255) csum[blockIdx.x] = lds[255];
}

__global__ __launch_bounds__(128) void k_scan2(
    const int* __restrict__ csum, int* __restrict__ coff, int nchunk)
{
    __shared__ int lds[128];
    int tid = threadIdx.x;
    int v = (tid < nchunk) ? csum[tid] : 0;
    lds[tid] = v;
    __syncthreads();
    for (int off = 1; off < 128; off <<= 1) {
        int add = (tid >= off) ? lds[tid - off] : 0;
        __syncthreads();
        lds[tid] += add;
        __syncthreads();
    }
    coff[tid] = lds[tid] - v;   // exclusive
}

__global__ __launch_bounds__(256) void k_scan3(
    int* __restrict__ arr, const int* __restrict__ coff, int n)
{
    int off = coff[blockIdx.x];
    int i0 = blockIdx.x * 1024 + threadIdx.x * 4;
    #pragma unroll
    for (int k = 0; k < 4; ++k)
        if (i0 + k < n) arr[i0 + k] += off;
    if (blockIdx.x == 0 && threadIdx.x == 0) arr[n] = NE;   // sentinel (total)
}

// ---- fill pass 1: atomic-free bucket partition via per-block LDS cursors.
//      8B record {src(17b) | w0(15b)<<17 ; w1(15b) | w2(15b)<<15}; softplus>=0
//      -> sign-free bf16, float reconstruction = wb<<16. ----
__global__ __launch_bounds__(1024) void k_fill(
    const int* __restrict__ ei, const float* __restrict__ ea,
    const float* __restrict__ mw, const float* __restrict__ mb,
    const int* __restrict__ goff, uint2* __restrict__ stg,
    unsigned char* __restrict__ stgd)
{
    __shared__ int lcur[NBKT];
    int bi = blockIdx.x;
    for (int t = threadIdx.x; t < NBKT; t += 1024) lcur[t] = goff[t * NBLK + bi];
    __syncthreads();
    float wl[3][8], bl[3];
    #pragma unroll
    for (int l = 0; l < 3; ++l) {
        bl[l] = mb[l];
        #pragma unroll
        for (int k = 0; k < 8; ++k) wl[l][k] = mw[l * 8 + k];
    }
    const float4* ea4 = (const float4*)ea;
    int e1 = bi * EPB + EPB;
    for (int e = bi * EPB + threadIdx.x; e < e1; e += 1024) {
        float4 a0 = ea4[2 * e], a1 = ea4[2 * e + 1];
        float av[8] = {a0.x, a0.y, a0.z, a0.w, a1.x, a1.y, a1.z, a1.w};
        unsigned int wb[3];
        #pragma unroll
        for (int l = 0; l < 3; ++l) {
            float xx = bl[l];
            #pragma unroll
            for (int k = 0; k < 8; ++k) xx += av[k] * wl[l][k];
            float sp = fmaxf(xx, 0.f) + log1pf(expf(-fabsf(xx)));  // stable softplus
            wb[l] = f2bf(sp) & 0x7FFFu;
        }
        int src = ei[e], dst = ei[NE + e];
        int slot = atomicAdd(&lcur[dst >> 8], 1);   // LDS atomic, block-local
        uint2 rec;
        rec.x = (unsigned int)src | (wb[0] << 17);
        rec.y = wb[1] | (wb[2] << 15);
        stg[slot] = rec;
        stgd[slot] = (unsigned char)(dst & 255);
    }
}

// ---- fill pass 2: per-bucket node grouping via LDS ranks -> final CSR pk ----
__global__ __launch_bounds__(256) void k_fill2(
    const int* __restrict__ base, const uint2* __restrict__ stg,
    const unsigned char* __restrict__ stgd, uint2* __restrict__ pk)
{
    __shared__ int bl[256];
    __shared__ int cnt[256];
    int b = blockIdx.x;
    int n0 = b * 256;
    int t = threadIdx.x;
    if (n0 + t < NN) { bl[t] = base[n0 + t]; }
    cnt[t] = 0;
    __syncthreads();
    int s0 = base[n0];
    int s1 = (n0 + 256 <= NN) ? base[n0 + 256] : NE;
    for (int s = s0 + t; s < s1; s += 256) {
        uint2 rec = stg[s];
        int dl = stgd[s];
        int r = atomicAdd(&cnt[dl], 1);
        pk[bl[dl] + r] = rec;
    }
}

// ---- per-layer weight decode: float(wb) = wb << 16 (sign-free bf16) ----
template<int L>
__device__ inline float dec_w(uint2 p) {
    if (L == 0) return __uint_as_float((p.x >> 17) << 16);
    if (L == 1) return __uint_as_float((p.y & 0x7FFFu) << 16);
    return __uint_as_float((p.y >> 15) << 16);
}

// ---- atomic-free aggregation: 8 lanes/node (8 nodes per wave), uint4 bf16 gathers
// aout[n] = sum_e w_e * hb[src_e] - (sum_e w_e) * h[n]   (fold term in fp32)
template<int L>
__global__ __launch_bounds__(256) void k_agg(
    const int* __restrict__ base, const uint2* __restrict__ pk,
    const unsigned short* __restrict__ hb, const float* __restrict__ h,
    float* __restrict__ aout)
{
    int lane = threadIdx.x & 63;
    int sub = lane & 7;      // channel group: channels [8*sub, 8*sub+8)
    int g = lane >> 3;       // node slot within wave (0..7)
    int wid = (blockIdx.x * blockDim.x + threadIdx.x) >> 6;
    int nwave = (gridDim.x * blockDim.x) >> 6;
    for (int n = wid * 8 + g; n < NN; n += nwave * 8) {
        int s = base[n], e2 = base[n + 1];
        float a0 = 0.f, a1 = 0.f, a2 = 0.f, a3 = 0.f;
        float a4 = 0.f, a5 = 0.f, a6 = 0.f, a7 = 0.f, wsn = 0.f;
        int sl = s;
        for (; sl + 4 <= e2; sl += 4) {
            uint2 p0 = pk[sl], p1 = pk[sl + 1], p2 = pk[sl + 2], p3 = pk[sl + 3];
            uint4 v0 = *(const uint4*)(hb + (((size_t)(p0.x & 0x1FFFF)) << 6) + (sub << 3));
            uint4 v1 = *(const uint4*)(hb + (((size_t)(p1.x & 0x1FFFF)) << 6) + (sub << 3));
            uint4 v2 = *(const uint4*)(hb + (((size_t)(p2.x & 0x1FFFF)) << 6) + (sub << 3));
            uint4 v3 = *(const uint4*)(hb + (((size_t)(p3.x & 0x1FFFF)) << 6) + (sub << 3));
            float w0 = dec_w<L>(p0), w1 = dec_w<L>(p1), w2 = dec_w<L>(p2), w3 = dec_w<L>(p3);
            a0 += w0 * bflo(v0.x); a1 += w0 * bfhi(v0.x); a2 += w0 * bflo(v0.y); a3 += w0 * bfhi(v0.y);
            a4 += w0 * bflo(v0.z); a5 += w0 * bfhi(v0.z); a6 += w0 * bflo(v0.w); a7 += w0 * bfhi(v0.w);
            a0 += w1 * bflo(v1.x); a1 += w1 * bfhi(v1.x); a2 += w1 * bflo(v1.y); a3 += w1 * bfhi(v1.y);
            a4 += w1 * bflo(v1.z); a5 += w1 * bfhi(v1.z); a6 += w1 * bflo(v1.w); a7 += w1 * bfhi(v1.w);
            a0 += w2 * bflo(v2.x); a1 += w2 * bfhi(v2.x); a2 += w2 * bflo(v2.y); a3 += w2 * bfhi(v2.y);
            a4 += w2 * bflo(v2.z); a5 += w2 * bfhi(v2.z); a6 += w2 * bflo(v2.w); a7 += w2 * bfhi(v2.w);
            a0 += w3 * bflo(v3.x); a1 += w3 * bfhi(v3.x); a2 += w3 * bflo(v3.y); a3 += w3 * bfhi(v3.y);
            a4 += w3 * bflo(v3.z); a5 += w3 * bfhi(v3.z); a6 += w3 * bflo(v3.w); a7 += w3 * bfhi(v3.w);
            wsn += w0 + w1 + w2 + w3;
        }
        for (; sl < e2; ++sl) {
            uint2 p = pk[sl];
            uint4 v = *(const uint4*)(hb + (((size_t)(p.x & 0x1FFFF)) << 6) + (sub << 3));
            float w = dec_w<L>(p);
            a0 += w * bflo(v.x); a1 += w * bfhi(v.x); a2 += w * bflo(v.y); a3 += w * bfhi(v.y);
            a4 += w * bflo(v.z); a5 += w * bfhi(v.z); a6 += w * bflo(v.w); a7 += w * bfhi(v.w);
            wsn += w;
        }
        const float* hrow = h + (size_t)n * 64 + sub * 8;
        float4 h0 = *(const float4*)hrow;
        float4 h1 = *(const float4*)(hrow + 4);
        float* orow = aout + (size_t)n * 64 + sub * 8;
        float4 o0 = {a0 - wsn * h0.x, a1 - wsn * h0.y, a2 - wsn * h0.z, a3 - wsn * h0.w};
        float4 o1 = {a4 - wsn * h1.x, a5 - wsn * h1.y, a6 - wsn * h1.z, a7 - wsn * h1.w};
        *(float4*)orow = o0;
        *(float4*)(orow + 4) = o1;
    }
}

// ---- fused: y = relu(a @ W^T + b) ; LN ; +residual ; emit fp32 + bf16 shadow ----
// NOTE: hout may alias a (per-row in-place) -> no __restrict on those two.
__global__ __launch_bounds__(256) void k_node(
    const float* a, const float* __restrict__ hin, float* hout,
    unsigned short* __restrict__ hbout,
    const float* __restrict__ wt, const float* __restrict__ bias,
    const float* __restrict__ gamma, const float* __restrict__ beta)
{
    int n0 = blockIdx.x * blockDim.x + threadIdx.x;
    int stride = gridDim.x * blockDim.x;
    const float4* a4 = (const float4*)a;
    const float4* hin4 = (const float4*)hin;
    float4* ho4 = (float4*)hout;
    ushort4* hb4 = (ushort4*)hbout;
    for (int n = n0; n < NN; n += stride) {
        float y[64];
        #pragma unroll
        for (int j = 0; j < 64; ++j) y[j] = bias[j];
        #pragma unroll 2
        for (int k4 = 0; k4 < 16; ++k4) {
            float4 gg = a4[n * 16 + k4];
            float av[4] = {gg.x, gg.y, gg.z, gg.w};
            #pragma unroll
            for (int kk = 0; kk < 4; ++kk) {
                const float* wr = wt + (k4 * 4 + kk) * 64;
                #pragma unroll
                for (int j = 0; j < 64; ++j) y[j] += av[kk] * wr[j];
            }
        }
        float s = 0.f, s2 = 0.f;
        #pragma unroll
        for (int j = 0; j < 64; ++j) {
            y[j] = fmaxf(y[j], 0.f);
            s += y[j]; s2 += y[j] * y[j];
        }
        float mu = s * (1.f / 64.f);
        float var = s2 * (1.f / 64.f) - mu * mu;
        float inv = rsqrtf(var + 1e-5f);
        #pragma unroll
        for (int j4 = 0; j4 < 16; ++j4) {
            float4 hh = hin4[n * 16 + j4];
            float4 o;
            o.x = (y[4*j4+0] - mu) * inv * gamma[4*j4+0] + beta[4*j4+0] + hh.x;
            o.y = (y[4*j4+1] - mu) * inv * gamma[4*j4+1] + beta[4*j4+1] + hh.y;
            o.z = (y[4*j4+2] - mu) * inv * gamma[4*j4+2] + beta[4*j4+2] + hh.z;
            o.w = (y[4*j4+3] - mu) * inv * gamma[4*j4+3] + beta[4*j4+3] + hh.w;
            ho4[n * 16 + j4] = o;
            if (hbout)
                hb4[n * 16 + j4] = make_ushort4(f2bf(o.x), f2bf(o.y), f2bf(o.z), f2bf(o.w));
        }
    }
}

// ---- final fc: out = h @ fc_w^T + fc_b ----
__global__ __launch_bounds__(256) void k_fc(
    const float* __restrict__ hin, float* __restrict__ out,
    const float* __restrict__ wt, const float* __restrict__ bias)
{
    int n0 = blockIdx.x * blockDim.x + threadIdx.x;
    int stride = gridDim.x * blockDim.x;
    const float4* hin4 = (const float4*)hin;
    float4* o4 = (float4*)out;
    for (int n = n0; n < NN; n += stride) {
        float y[64];
        #pragma unroll
        for (int j = 0; j < 64; ++j) y[j] = bias[j];
        #pragma unroll 2
        for (int k4 = 0; k4 < 16; ++k4) {
            float4 hh = hin4[n * 16 + k4];
            float hv[4] = {hh.x, hh.y, hh.z, hh.w};
            #pragma unroll
            for (int kk = 0; kk < 4; ++kk) {
                const float* wr = wt + (k4 * 4 + kk) * 64;
                #pragma unroll
                for (int j = 0; j < 64; ++j) y[j] += hv[kk] * wr[j];
            }
        }
        #pragma unroll
        for (int j4 = 0; j4 < 16; ++j4) {
            float4 o = {y[4*j4], y[4*j4+1], y[4*j4+2], y[4*j4+3]};
            o4[n * 16 + j4] = o;
        }
    }
}

extern "C" void kernel_launch(void* const* d_in, const int* in_sizes, int n_in,
                              void* d_out, int out_size, void* d_ws, size_t ws_size,
                              hipStream_t stream)
{
    const float* x     = (const float*)d_in[0];
    const int*   ei    = (const int*)d_in[1];
    const float* ea    = (const float*)d_in[2];
    const float* linw  = (const float*)d_in[3];
    const float* linb  = (const float*)d_in[4];
    const float* mw    = (const float*)d_in[5];
    const float* mb    = (const float*)d_in[6];
    const float* gamma = (const float*)d_in[7];
    const float* beta  = (const float*)d_in[8];
    const float* fcw   = (const float*)d_in[9];
    const float* fcb   = (const float*)d_in[10];
    float* out = (float*)d_out;

    // workspace layout (~92 MB); staging aliases buffers dead until agg writes them
    float*  A    = (float*)d_ws;                        // NN*64 f32
    float*  C    = A + (size_t)NN * 64;                 // NN*64 f32
    uint2*  pk   = (uint2*)(C + (size_t)NN * 64);       // NE uint2
    unsigned short* hb = (unsigned short*)(pk + NE);    // NN*64 bf16 (16B-aligned)
    float*  wt   = (float*)(hb + (size_t)NN * 64);      // 4*4096 f32
    int*    deg  = (int*)(wt + 4 * 4096);               // NN
    int*    base = deg + NN;                            // NN+1
    int*    gh   = base + NN + 1;                       // GH_N
    int*    goff = gh + GH_N;                           // GH_N+1
    int*    csum = goff + GH_N + 1;                     // 128
    int*    coff = csum + 128;                          // 128
    uint2*  stg  = (uint2*)C;                           // alias: dead until agg<0>
    unsigned char* stgd = (unsigned char*)A;            // alias: dead until agg<1>

    k_transpose<<<4, 256, 0, stream>>>(linw, fcw, wt);
    k_cvt<<<2048, 256, 0, stream>>>(x, hb);
    hipMemsetAsync(deg, 0, NN * sizeof(int), stream);
    k_hist2<<<NBLK, 1024, 0, stream>>>(ei, deg, gh);
    k_scan1<<<98, 256, 0, stream>>>(deg, base, csum, NN);
    k_scan2<<<1, 128, 0, stream>>>(csum, coff, 98);
    k_scan3<<<98, 256, 0, stream>>>(base, coff, NN);      // base[NN] = NE
    k_scan1<<<98, 256, 0, stream>>>(gh, goff, csum, GH_N);
    k_scan2<<<1, 128, 0, stream>>>(csum, coff, 98);
    k_scan3<<<98, 256, 0, stream>>>(goff, coff, GH_N);    // goff[GH_N] = NE
    k_fill<<<NBLK, 1024, 0, stream>>>(ei, ea, mw, mb, goff, stg, stgd);
    k_fill2<<<NBKT, 256, 0, stream>>>(base, stg, stgd, pk);

    // l0: x -> C ; l1: C -> A ; l2: A -> C   (hb holds bf16 of current h)
    k_agg<0><<<3125, 256, 0, stream>>>(base, pk, hb, x, C);
    k_node<<<512, 256, 0, stream>>>(C, x, C, hb, wt + 0 * 4096, linb + 0 * 64,
                                    gamma + 0 * 64, beta + 0 * 64);
    k_agg<1><<<3125, 256, 0, stream>>>(base, pk, hb, C, A);
    k_node<<<512, 256, 0, stream>>>(A, C, A, hb, wt + 1 * 4096, linb + 1 * 64,
                                    gamma + 1 * 64, beta + 1 * 64);
    k_agg<2><<<3125, 256, 0, stream>>>(base, pk, hb, A, C);
    k_node<<<512, 256, 0, stream>>>(C, A, C, (unsigned short*)nullptr,
                                    wt + 2 * 4096, linb + 2 * 64,
                                    gamma + 2 * 64, beta + 2 * 64);

    k_fc<<<512, 256, 0, stream>>>(C, out, wt + 3 * 4096, fcb);
}

// Round 9
// 756.652 us; speedup vs baseline: 3.7568x; 1.1609x over previous
//
#include <hip/hip_runtime.h>

#define NN 100000
#define NE 3200000
#define NBKT 391            // ceil(NN / 256) buckets of 256 nodes
#define NBLK 256            // partition blocks (fixed edge ranges)
#define EPB (NE / NBLK)     // 12500 edges per block
#define GH_N (NBKT * NBLK)  // 100096

__device__ inline unsigned short f2bf(float f) {   // round-to-nearest-even bf16
    unsigned int u = __float_as_uint(f);
    u += 0x7FFFu + ((u >> 16) & 1u);
    return (unsigned short)(u >> 16);
}
__device__ inline float bflo(unsigned int v) { return __uint_as_float(v << 16); }
__device__ inline float bfhi(unsigned int v) { return __uint_as_float(v & 0xFFFF0000u); }

// ---- transpose the 64x64 weight matrices (3 lin layers + final fc) ----
__global__ __launch_bounds__(256) void k_transpose(
    const float* __restrict__ linw, const float* __restrict__ fcw,
    float* __restrict__ wt)
{
    const float* src = (blockIdx.x < 3) ? (linw + blockIdx.x * 4096) : fcw;
    float* dst = wt + blockIdx.x * 4096;
    for (int i = threadIdx.x; i < 4096; i += 256)
        dst[(i & 63) * 64 + (i >> 6)] = src[i];   // wt[k][j] = w[j][k]
}

// ---- x (fp32) -> bf16 shadow ----
__global__ __launch_bounds__(256) void k_cvt(
    const float* __restrict__ x, unsigned short* __restrict__ hb)
{
    int stride = gridDim.x * blockDim.x;
    const float4* x4 = (const float4*)x;
    ushort4* hb4 = (ushort4*)hb;
    for (int i = blockIdx.x * blockDim.x + threadIdx.x; i < NN * 16; i += stride) {
        float4 v = x4[i];
        hb4[i] = make_ushort4(f2bf(v.x), f2bf(v.y), f2bf(v.z), f2bf(v.w));
    }
}

// ---- bucket histogram, LDS-only (NO global atomics) ----
__global__ __launch_bounds__(1024) void k_hist2(
    const int* __restrict__ ei, int* __restrict__ gh)
{
    __shared__ int lh[NBKT];
    for (int t = threadIdx.x; t < NBKT; t += 1024) lh[t] = 0;
    __syncthreads();
    int bi = blockIdx.x;
    int e1 = bi * EPB + EPB;
    for (int e = bi * EPB + threadIdx.x; e < e1; e += 1024)
        atomicAdd(&lh[ei[NE + e] >> 8], 1);
    __syncthreads();
    for (int t = threadIdx.x; t < NBKT; t += 1024)
        gh[t * NBLK + bi] = lh[t];
}

// ---- hierarchical exclusive scan over n elements (n <= 256*1024) ----
__global__ __launch_bounds__(256) void k_scan1(
    const int* __restrict__ in, int* __restrict__ out, int* __restrict__ csum, int n)
{
    __shared__ int lds[256];
    int tid = threadIdx.x;
    int i0 = blockIdx.x * 1024 + tid * 4;
    int d[4];
    #pragma unroll
    for (int k = 0; k < 4; ++k) d[k] = (i0 + k < n) ? in[i0 + k] : 0;
    int s = d[0] + d[1] + d[2] + d[3];
    lds[tid] = s;
    __syncthreads();
    for (int off = 1; off < 256; off <<= 1) {
        int add = (tid >= off) ? lds[tid - off] : 0;
        __syncthreads();
        lds[tid] += add;
        __syncthreads();
    }
    int excl = lds[tid] - s;
    if (i0 + 0 < n) out[i0 + 0] = excl;
    if (i0 + 1 < n) out[i0 + 1] = excl + d[0];
    if (i0 + 2 < n) out[i0 + 2] = excl + d[0] + d[1];
    if (i0 + 3 < n) out[i0 + 3] = excl + d[0] + d[1] + d[2];
    if (tid == 255) csum[blockIdx.x] = lds[255];
}

__global__ __launch_bounds__(128) void k_scan2(
    const int* __restrict__ csum, int* __restrict__ coff, int nchunk)
{
    __shared__ int lds[128];
    int tid = threadIdx.x;
    int v = (tid < nchunk) ? csum[tid] : 0;
    lds[tid] = v;
    __syncthreads();
    for (int off = 1; off < 128; off <<= 1) {
        int add = (tid >= off) ? lds[tid - off] : 0;
        __syncthreads();
        lds[tid] += add;
        __syncthreads();
    }
    coff[tid] = lds[tid] - v;   // exclusive
}

__global__ __launch_bounds__(256) void k_scan3(
    int* __restrict__ arr, const int* __restrict__ coff, int n)
{
    int off = coff[blockIdx.x];
    int i0 = blockIdx.x * 1024 + threadIdx.x * 4;
    #pragma unroll
    for (int k = 0; k < 4; ++k)
        if (i0 + k < n) arr[i0 + k] += off;
    if (blockIdx.x == 0 && threadIdx.x == 0) arr[n] = NE;   // sentinel (total)
}

// ---- fill pass 1: atomic-free bucket partition via per-block LDS cursors.
//      8B record {src(17b) | w0(15b)<<17 ; w1(15b) | w2(15b)<<15}; softplus>=0
//      -> sign-free bf16, float reconstruction = wb<<16. ----
__global__ __launch_bounds__(1024) void k_fill(
    const int* __restrict__ ei, const float* __restrict__ ea,
    const float* __restrict__ mw, const float* __restrict__ mb,
    const int* __restrict__ goff, uint2* __restrict__ stg,
    unsigned char* __restrict__ stgd)
{
    __shared__ int lcur[NBKT];
    int bi = blockIdx.x;
    for (int t = threadIdx.x; t < NBKT; t += 1024) lcur[t] = goff[t * NBLK + bi];
    __syncthreads();
    float wl[3][8], bl[3];
    #pragma unroll
    for (int l = 0; l < 3; ++l) {
        bl[l] = mb[l];
        #pragma unroll
        for (int k = 0; k < 8; ++k) wl[l][k] = mw[l * 8 + k];
    }
    const float4* ea4 = (const float4*)ea;
    int e1 = bi * EPB + EPB;
    for (int e = bi * EPB + threadIdx.x; e < e1; e += 1024) {
        float4 a0 = ea4[2 * e], a1 = ea4[2 * e + 1];
        float av[8] = {a0.x, a0.y, a0.z, a0.w, a1.x, a1.y, a1.z, a1.w};
        unsigned int wb[3];
        #pragma unroll
        for (int l = 0; l < 3; ++l) {
            float xx = bl[l];
            #pragma unroll
            for (int k = 0; k < 8; ++k) xx += av[k] * wl[l][k];
            float sp = fmaxf(xx, 0.f) + log1pf(expf(-fabsf(xx)));  // stable softplus
            wb[l] = f2bf(sp) & 0x7FFFu;
        }
        int src = ei[e], dst = ei[NE + e];
        int slot = atomicAdd(&lcur[dst >> 8], 1);   // LDS atomic, block-local
        uint2 rec;
        rec.x = (unsigned int)src | (wb[0] << 17);
        rec.y = wb[1] | (wb[2] << 15);
        stg[slot] = rec;
        stgd[slot] = (unsigned char)(dst & 255);
    }
}

// ---- fill pass 2 (3-phase): per-bucket node histogram -> base[] -> place pk ----
__global__ __launch_bounds__(256) void k_fill2(
    const int* __restrict__ goff, const uint2* __restrict__ stg,
    const unsigned char* __restrict__ stgd, uint2* __restrict__ pk,
    int* __restrict__ base)
{
    __shared__ int cnt[256];
    __shared__ int lds[256];
    __shared__ int pos[256];
    int b = blockIdx.x;
    int n0 = b * 256;
    int t = threadIdx.x;
    int s0 = goff[b * NBLK];
    int s1 = goff[(b + 1) * NBLK];   // goff[GH_N] = NE sentinel
    // phase a: per-node counts within bucket
    cnt[t] = 0;
    __syncthreads();
    for (int s = s0 + t; s < s1; s += 256)
        atomicAdd(&cnt[stgd[s]], 1);
    __syncthreads();
    // phase b: exclusive scan of cnt -> base
    int v = cnt[t];
    lds[t] = v;
    __syncthreads();
    for (int off = 1; off < 256; off <<= 1) {
        int add = (t >= off) ? lds[t - off] : 0;
        __syncthreads();
        lds[t] += add;
        __syncthreads();
    }
    int start = s0 + lds[t] - v;
    pos[t] = start;
    if (n0 + t < NN) base[n0 + t] = start;
    if (b == 0 && t == 0) base[NN] = NE;
    __syncthreads();
    // phase c: place records grouped by node
    for (int s = s0 + t; s < s1; s += 256) {
        uint2 rec = stg[s];
        int dl = stgd[s];
        int r = atomicAdd(&pos[dl], 1);
        pk[r] = rec;
    }
}

// ---- per-layer weight decode: float(wb) = wb << 16 (sign-free bf16) ----
template<int L>
__device__ inline float dec_w(uint2 p) {
    if (L == 0) return __uint_as_float((p.x >> 17) << 16);
    if (L == 1) return __uint_as_float((p.y & 0x7FFFu) << 16);
    return __uint_as_float((p.y >> 15) << 16);
}

// ---- atomic-free aggregation: 8 lanes/node (8 nodes per wave), uint4 bf16 gathers
// aout[n] = sum_e w_e * hb[src_e] - (sum_e w_e) * h[n]   (fold term in fp32)
template<int L>
__global__ __launch_bounds__(256) void k_agg(
    const int* __restrict__ base, const uint2* __restrict__ pk,
    const unsigned short* __restrict__ hb, const float* __restrict__ h,
    float* __restrict__ aout)
{
    int lane = threadIdx.x & 63;
    int sub = lane & 7;      // channel group: channels [8*sub, 8*sub+8)
    int g = lane >> 3;       // node slot within wave (0..7)
    int wid = (blockIdx.x * blockDim.x + threadIdx.x) >> 6;
    int nwave = (gridDim.x * blockDim.x) >> 6;
    for (int n = wid * 8 + g; n < NN; n += nwave * 8) {
        int s = base[n], e2 = base[n + 1];
        float a0 = 0.f, a1 = 0.f, a2 = 0.f, a3 = 0.f;
        float a4 = 0.f, a5 = 0.f, a6 = 0.f, a7 = 0.f, wsn = 0.f;
        int sl = s;
        for (; sl + 4 <= e2; sl += 4) {
            uint2 p0 = pk[sl], p1 = pk[sl + 1], p2 = pk[sl + 2], p3 = pk[sl + 3];
            uint4 v0 = *(const uint4*)(hb + (((size_t)(p0.x & 0x1FFFF)) << 6) + (sub << 3));
            uint4 v1 = *(const uint4*)(hb + (((size_t)(p1.x & 0x1FFFF)) << 6) + (sub << 3));
            uint4 v2 = *(const uint4*)(hb + (((size_t)(p2.x & 0x1FFFF)) << 6) + (sub << 3));
            uint4 v3 = *(const uint4*)(hb + (((size_t)(p3.x & 0x1FFFF)) << 6) + (sub << 3));
            float w0 = dec_w<L>(p0), w1 = dec_w<L>(p1), w2 = dec_w<L>(p2), w3 = dec_w<L>(p3);
            a0 += w0 * bflo(v0.x); a1 += w0 * bfhi(v0.x); a2 += w0 * bflo(v0.y); a3 += w0 * bfhi(v0.y);
            a4 += w0 * bflo(v0.z); a5 += w0 * bfhi(v0.z); a6 += w0 * bflo(v0.w); a7 += w0 * bfhi(v0.w);
            a0 += w1 * bflo(v1.x); a1 += w1 * bfhi(v1.x); a2 += w1 * bflo(v1.y); a3 += w1 * bfhi(v1.y);
            a4 += w1 * bflo(v1.z); a5 += w1 * bfhi(v1.z); a6 += w1 * bflo(v1.w); a7 += w1 * bfhi(v1.w);
            a0 += w2 * bflo(v2.x); a1 += w2 * bfhi(v2.x); a2 += w2 * bflo(v2.y); a3 += w2 * bfhi(v2.y);
            a4 += w2 * bflo(v2.z); a5 += w2 * bfhi(v2.z); a6 += w2 * bflo(v2.w); a7 += w2 * bfhi(v2.w);
            a0 += w3 * bflo(v3.x); a1 += w3 * bfhi(v3.x); a2 += w3 * bflo(v3.y); a3 += w3 * bfhi(v3.y);
            a4 += w3 * bflo(v3.z); a5 += w3 * bfhi(v3.z); a6 += w3 * bflo(v3.w); a7 += w3 * bfhi(v3.w);
            wsn += w0 + w1 + w2 + w3;
        }
        for (; sl < e2; ++sl) {
            uint2 p = pk[sl];
            uint4 v = *(const uint4*)(hb + (((size_t)(p.x & 0x1FFFF)) << 6) + (sub << 3));
            float w = dec_w<L>(p);
            a0 += w * bflo(v.x); a1 += w * bfhi(v.x); a2 += w * bflo(v.y); a3 += w * bfhi(v.y);
            a4 += w * bflo(v.z); a5 += w * bfhi(v.z); a6 += w * bflo(v.w); a7 += w * bfhi(v.w);
            wsn += w;
        }
        const float* hrow = h + (size_t)n * 64 + sub * 8;
        float4 h0 = *(const float4*)hrow;
        float4 h1 = *(const float4*)(hrow + 4);
        float* orow = aout + (size_t)n * 64 + sub * 8;
        float4 o0 = {a0 - wsn * h0.x, a1 - wsn * h0.y, a2 - wsn * h0.z, a3 - wsn * h0.w};
        float4 o1 = {a4 - wsn * h1.x, a5 - wsn * h1.y, a6 - wsn * h1.z, a7 - wsn * h1.w};
        *(float4*)orow = o0;
        *(float4*)(orow + 4) = o1;
    }
}

// ---- fused: y = relu(a @ W^T + b) ; LN ; +residual ; emit fp32 + bf16 shadow ----
// NOTE: hout may alias a (per-row in-place) -> no __restrict on those two.
__global__ __launch_bounds__(256) void k_node(
    const float* a, const float* __restrict__ hin, float* hout,
    unsigned short* __restrict__ hbout,
    const float* __restrict__ wt, const float* __restrict__ bias,
    const float* __restrict__ gamma, const float* __restrict__ beta)
{
    int n0 = blockIdx.x * blockDim.x + threadIdx.x;
    int stride = gridDim.x * blockDim.x;
    const float4* a4 = (const float4*)a;
    const float4* hin4 = (const float4*)hin;
    float4* ho4 = (float4*)hout;
    ushort4* hb4 = (ushort4*)hbout;
    for (int n = n0; n < NN; n += stride) {
        float y[64];
        #pragma unroll
        for (int j = 0; j < 64; ++j) y[j] = bias[j];
        #pragma unroll 2
        for (int k4 = 0; k4 < 16; ++k4) {
            float4 gg = a4[n * 16 + k4];
            float av[4] = {gg.x, gg.y, gg.z, gg.w};
            #pragma unroll
            for (int kk = 0; kk < 4; ++kk) {
                const float* wr = wt + (k4 * 4 + kk) * 64;
                #pragma unroll
                for (int j = 0; j < 64; ++j) y[j] += av[kk] * wr[j];
            }
        }
        float s = 0.f, s2 = 0.f;
        #pragma unroll
        for (int j = 0; j < 64; ++j) {
            y[j] = fmaxf(y[j], 0.f);
            s += y[j]; s2 += y[j] * y[j];
        }
        float mu = s * (1.f / 64.f);
        float var = s2 * (1.f / 64.f) - mu * mu;
        float inv = rsqrtf(var + 1e-5f);
        #pragma unroll
        for (int j4 = 0; j4 < 16; ++j4) {
            float4 hh = hin4[n * 16 + j4];
            float4 o;
            o.x = (y[4*j4+0] - mu) * inv * gamma[4*j4+0] + beta[4*j4+0] + hh.x;
            o.y = (y[4*j4+1] - mu) * inv * gamma[4*j4+1] + beta[4*j4+1] + hh.y;
            o.z = (y[4*j4+2] - mu) * inv * gamma[4*j4+2] + beta[4*j4+2] + hh.z;
            o.w = (y[4*j4+3] - mu) * inv * gamma[4*j4+3] + beta[4*j4+3] + hh.w;
            ho4[n * 16 + j4] = o;
            if (hbout)
                hb4[n * 16 + j4] = make_ushort4(f2bf(o.x), f2bf(o.y), f2bf(o.z), f2bf(o.w));
        }
    }
}

// ---- final fc: out = h @ fc_w^T + fc_b ----
__global__ __launch_bounds__(256) void k_fc(
    const float* __restrict__ hin, float* __restrict__ out,
    const float* __restrict__ wt, const float* __restrict__ bias)
{
    int n0 = blockIdx.x * blockDim.x + threadIdx.x;
    int stride = gridDim.x * blockDim.x;
    const float4* hin4 = (const float4*)hin;
    float4* o4 = (float4*)out;
    for (int n = n0; n < NN; n += stride) {
        float y[64];
        #pragma unroll
        for (int j = 0; j < 64; ++j) y[j] = bias[j];
        #pragma unroll 2
        for (int k4 = 0; k4 < 16; ++k4) {
            float4 hh = hin4[n * 16 + k4];
            float hv[4] = {hh.x, hh.y, hh.z, hh.w};
            #pragma unroll
            for (int kk = 0; kk < 4; ++kk) {
                const float* wr = wt + (k4 * 4 + kk) * 64;
                #pragma unroll
                for (int j = 0; j < 64; ++j) y[j] += hv[kk] * wr[j];
            }
        }
        #pragma unroll
        for (int j4 = 0; j4 < 16; ++j4) {
            float4 o = {y[4*j4], y[4*j4+1], y[4*j4+2], y[4*j4+3]};
            o4[n * 16 + j4] = o;
        }
    }
}

extern "C" void kernel_launch(void* const* d_in, const int* in_sizes, int n_in,
                              void* d_out, int out_size, void* d_ws, size_t ws_size,
                              hipStream_t stream)
{
    const float* x     = (const float*)d_in[0];
    const int*   ei    = (const int*)d_in[1];
    const float* ea    = (const float*)d_in[2];
    const float* linw  = (const float*)d_in[3];
    const float* linb  = (const float*)d_in[4];
    const float* mw    = (const float*)d_in[5];
    const float* mb    = (const float*)d_in[6];
    const float* gamma = (const float*)d_in[7];
    const float* beta  = (const float*)d_in[8];
    const float* fcw   = (const float*)d_in[9];
    const float* fcb   = (const float*)d_in[10];
    float* out = (float*)d_out;

    // workspace layout (~92 MB); staging aliases buffers dead until agg writes them
    float*  A    = (float*)d_ws;                        // NN*64 f32
    float*  C    = A + (size_t)NN * 64;                 // NN*64 f32
    uint2*  pk   = (uint2*)(C + (size_t)NN * 64);       // NE uint2
    unsigned short* hb = (unsigned short*)(pk + NE);    // NN*64 bf16 (16B-aligned)
    float*  wt   = (float*)(hb + (size_t)NN * 64);      // 4*4096 f32
    int*    base = (int*)(wt + 4 * 4096);               // NN+1
    int*    gh   = base + NN + 1;                       // GH_N
    int*    goff = gh + GH_N;                           // GH_N+1
    int*    csum = goff + GH_N + 1;                     // 128
    int*    coff = csum + 128;                          // 128
    uint2*  stg  = (uint2*)C;                           // alias: dead until agg<0>
    unsigned char* stgd = (unsigned char*)A;            // alias: dead until agg<1>

    k_transpose<<<4, 256, 0, stream>>>(linw, fcw, wt);
    k_cvt<<<2048, 256, 0, stream>>>(x, hb);
    k_hist2<<<NBLK, 1024, 0, stream>>>(ei, gh);
    k_scan1<<<98, 256, 0, stream>>>(gh, goff, csum, GH_N);
    k_scan2<<<1, 128, 0, stream>>>(csum, coff, 98);
    k_scan3<<<98, 256, 0, stream>>>(goff, coff, GH_N);    // goff[GH_N] = NE
    k_fill<<<NBLK, 1024, 0, stream>>>(ei, ea, mw, mb, goff, stg, stgd);
    k_fill2<<<NBKT, 256, 0, stream>>>(goff, stg, stgd, pk, base);

    // l0: x -> C ; l1: C -> A ; l2: A -> C   (hb holds bf16 of current h)
    k_agg<0><<<3125, 256, 0, stream>>>(base, pk, hb, x, C);
    k_node<<<512, 256, 0, stream>>>(C, x, C, hb, wt + 0 * 4096, linb + 0 * 64,
                                    gamma + 0 * 64, beta + 0 * 64);
    k_agg<1><<<3125, 256, 0, stream>>>(base, pk, hb, C, A);
    k_node<<<512, 256, 0, stream>>>(A, C, A, hb, wt + 1 * 4096, linb + 1 * 64,
                                    gamma + 1 * 64, beta + 1 * 64);
    k_agg<2><<<3125, 256, 0, stream>>>(base, pk, hb, A, C);
    k_node<<<512, 256, 0, stream>>>(C, A, C, (unsigned short*)nullptr,
                                    wt + 2 * 4096, linb + 2 * 64,
                                    gamma + 2 * 64, beta + 2 * 64);

    k_fc<<<512, 256, 0, stream>>>(C, out, wt + 3 * 4096, fcb);
}